// Round 1
// baseline (373.959 us; speedup 1.0000x reference)
//
#include <hip/hip_runtime.h>

#define NB_B  2
#define NB_Q  10000
#define NB_D  256
#define NB_NH 8
#define NB_NL 4
#define NB_NP 4
#define NB_HD 32
#define NB_S  21760   // 128*128 + 64*64 + 32*32 + 16*16

// ---------------------------------------------------------------------------
// Kernel 1: v = value @ Wv + bv, stored as vt[b][h][s][hd]  (B,NH,S,HD)
// 8 rows per block, 256 threads (one output column per thread).
// ---------------------------------------------------------------------------
__global__ __launch_bounds__(256) void k_vproj(const float* __restrict__ value,
                                               const float* __restrict__ Wv,
                                               const float* __restrict__ bv,
                                               float* __restrict__ vt)
{
    __shared__ float vs[8][NB_D];
    const int t = threadIdx.x;
    const int row0 = blockIdx.x * 8;   // row in [0, B*S), B*S % 8 == 0
#pragma unroll
    for (int r = 0; r < 8; ++r)
        vs[r][t] = value[(row0 + r) * NB_D + t];
    __syncthreads();

    float acc[8];
    const float bias = bv[t];
#pragma unroll
    for (int r = 0; r < 8; ++r) acc[r] = bias;

    for (int k = 0; k < NB_D; k += 4) {
        const float w0 = Wv[(k + 0) * NB_D + t];
        const float w1 = Wv[(k + 1) * NB_D + t];
        const float w2 = Wv[(k + 2) * NB_D + t];
        const float w3 = Wv[(k + 3) * NB_D + t];
#pragma unroll
        for (int r = 0; r < 8; ++r) {
            const float4 q = *reinterpret_cast<const float4*>(&vs[r][k]);
            acc[r] = fmaf(q.x, w0, acc[r]);
            acc[r] = fmaf(q.y, w1, acc[r]);
            acc[r] = fmaf(q.z, w2, acc[r]);
            acc[r] = fmaf(q.w, w3, acc[r]);
        }
    }

    const int h = t >> 5, hd = t & 31;
#pragma unroll
    for (int r = 0; r < 8; ++r) {
        const int row = row0 + r;
        const int b = row / NB_S;
        const int s = row - b * NB_S;
        vt[((b * NB_NH + h) * NB_S + s) * NB_HD + hd] = acc[r];
    }
}

// ---------------------------------------------------------------------------
// Kernel 2: per block of 8 queries:
//   - offsets  = q @ Ws + bs  (256 cols)  -> pixel sample coords
//   - logits   = q @ Wa + ba  (128 cols)  -> softmax over 16 per head
//   - bilinear sample vt, weighted-accumulate -> tmp[b][q][h*32+hd]
// ---------------------------------------------------------------------------
__global__ __launch_bounds__(256) void k_sample(const float* __restrict__ query,
                                                const float* __restrict__ refp,
                                                const float* __restrict__ Ws,
                                                const float* __restrict__ bs,
                                                const float* __restrict__ Wa,
                                                const float* __restrict__ ba,
                                                const float* __restrict__ vt,
                                                float* __restrict__ tmp)
{
    __shared__ float qs[8][NB_D];
    __shared__ float sx[8][128];
    __shared__ float sy[8][128];
    __shared__ float sw[8][128];

    const int t = threadIdx.x;
    const int row0 = blockIdx.x * 8;   // row in [0, B*Q), Q % 8 == 0 -> same b
#pragma unroll
    for (int r = 0; r < 8; ++r)
        qs[r][t] = query[(row0 + r) * NB_D + t];
    __syncthreads();

    // ---- sampling offset columns (Ws has 256 cols: ((h*4+l)*4+p)*2+c) ----
    {
        float acc[8];
        const float bias = bs[t];
#pragma unroll
        for (int r = 0; r < 8; ++r) acc[r] = bias;
        for (int k = 0; k < NB_D; k += 4) {
            const float w0 = Ws[(k + 0) * 256 + t];
            const float w1 = Ws[(k + 1) * 256 + t];
            const float w2 = Ws[(k + 2) * 256 + t];
            const float w3 = Ws[(k + 3) * 256 + t];
#pragma unroll
            for (int r = 0; r < 8; ++r) {
                const float4 q = *reinterpret_cast<const float4*>(&qs[r][k]);
                acc[r] = fmaf(q.x, w0, acc[r]);
                acc[r] = fmaf(q.y, w1, acc[r]);
                acc[r] = fmaf(q.z, w2, acc[r]);
                acc[r] = fmaf(q.w, w3, acc[r]);
            }
        }
        const int c = t & 1, p = (t >> 1) & 3, l = (t >> 3) & 3, h = t >> 5;
        const float dim = (float)(128 >> l);   // square levels: W==H
        const int si = h * 16 + l * 4 + p;
#pragma unroll
        for (int r = 0; r < 8; ++r) {
            const int row = row0 + r;
            const float rp = refp[(row * NB_NL + l) * 2 + c];
            // pixel coord = ref*dim + off - 0.5
            const float coord = rp * dim + acc[r] - 0.5f;
            if (c == 0) sx[r][si] = coord;
            else        sy[r][si] = coord;
        }
    }

    // ---- attention logits (Wa has 128 cols: h*16 + l*4 + p) ----
    {
        const int ta = t & 127;
        const int rb = (t >> 7) * 4;   // rows rb..rb+3
        float acc[4];
        const float bias = ba[ta];
#pragma unroll
        for (int j = 0; j < 4; ++j) acc[j] = bias;
        for (int k = 0; k < NB_D; k += 4) {
            const float w0 = Wa[(k + 0) * 128 + ta];
            const float w1 = Wa[(k + 1) * 128 + ta];
            const float w2 = Wa[(k + 2) * 128 + ta];
            const float w3 = Wa[(k + 3) * 128 + ta];
#pragma unroll
            for (int j = 0; j < 4; ++j) {
                const float4 q = *reinterpret_cast<const float4*>(&qs[rb + j][k]);
                acc[j] = fmaf(q.x, w0, acc[j]);
                acc[j] = fmaf(q.y, w1, acc[j]);
                acc[j] = fmaf(q.z, w2, acc[j]);
                acc[j] = fmaf(q.w, w3, acc[j]);
            }
        }
#pragma unroll
        for (int j = 0; j < 4; ++j) sw[rb + j][ta] = acc[j];
    }
    __syncthreads();

    // ---- softmax over 16 per (row, head) ----
    if (t < 64) {
        const int r = t >> 3, h = t & 7;
        float* pw = &sw[r][h * 16];
        float m = pw[0];
#pragma unroll
        for (int i = 1; i < 16; ++i) m = fmaxf(m, pw[i]);
        float ssum = 0.f;
#pragma unroll
        for (int i = 0; i < 16; ++i) { const float e = expf(pw[i] - m); pw[i] = e; ssum += e; }
        const float inv = 1.f / ssum;
#pragma unroll
        for (int i = 0; i < 16; ++i) pw[i] *= inv;
    }
    __syncthreads();

    // ---- bilinear sampling + weighted accumulate ----
    const int lane = t & 63;
    const int wv = t >> 6;             // 4 waves
    const int h  = wv * 2 + (lane >> 5);
    const int hd = lane & 31;
    const int b  = row0 / NB_Q;
    const float* vbase = vt + (size_t)(b * NB_NH + h) * (NB_S * NB_HD);
    const int startL[4] = {0, 16384, 20480, 21504};

    for (int r = 0; r < 8; ++r) {
        float acc = 0.f;
#pragma unroll
        for (int l = 0; l < 4; ++l) {
            const int dimL = 128 >> l;
            const float* vlev = vbase + startL[l] * NB_HD + hd;
#pragma unroll
            for (int p = 0; p < 4; ++p) {
                const int si = h * 16 + l * 4 + p;
                const float x = sx[r][si];
                const float y = sy[r][si];
                const float w = sw[r][si];
                const float x0f = floorf(x), y0f = floorf(y);
                const float lx = x - x0f, ly = y - y0f;
                const int ix = (int)x0f, iy = (int)y0f;
                float v00 = 0.f, v01 = 0.f, v10 = 0.f, v11 = 0.f;
                const bool x0in = (ix >= 0) & (ix < dimL);
                const bool x1in = (ix + 1 >= 0) & (ix + 1 < dimL);
                if ((iy >= 0) & (iy < dimL)) {
                    const float* rp = vlev + (iy * dimL) * NB_HD;
                    if (x0in) v00 = rp[ix * NB_HD];
                    if (x1in) v01 = rp[(ix + 1) * NB_HD];
                }
                if ((iy + 1 >= 0) & (iy + 1 < dimL)) {
                    const float* rp = vlev + ((iy + 1) * dimL) * NB_HD;
                    if (x0in) v10 = rp[ix * NB_HD];
                    if (x1in) v11 = rp[(ix + 1) * NB_HD];
                }
                const float vxy = (v00 * (1.f - lx) + v01 * lx) * (1.f - ly)
                                + (v10 * (1.f - lx) + v11 * lx) * ly;
                acc = fmaf(w, vxy, acc);
            }
        }
        tmp[(row0 + r) * NB_D + h * NB_HD + hd] = acc;
    }
}

// ---------------------------------------------------------------------------
// Kernel 3: out = tmp @ Wo + bo   (B*Q rows)
// ---------------------------------------------------------------------------
__global__ __launch_bounds__(256) void k_oproj(const float* __restrict__ tmp,
                                               const float* __restrict__ Wo,
                                               const float* __restrict__ bo,
                                               float* __restrict__ out)
{
    __shared__ float vs[8][NB_D];
    const int t = threadIdx.x;
    const int row0 = blockIdx.x * 8;   // row in [0, B*Q)
#pragma unroll
    for (int r = 0; r < 8; ++r)
        vs[r][t] = tmp[(row0 + r) * NB_D + t];
    __syncthreads();

    float acc[8];
    const float bias = bo[t];
#pragma unroll
    for (int r = 0; r < 8; ++r) acc[r] = bias;

    for (int k = 0; k < NB_D; k += 4) {
        const float w0 = Wo[(k + 0) * NB_D + t];
        const float w1 = Wo[(k + 1) * NB_D + t];
        const float w2 = Wo[(k + 2) * NB_D + t];
        const float w3 = Wo[(k + 3) * NB_D + t];
#pragma unroll
        for (int r = 0; r < 8; ++r) {
            const float4 q = *reinterpret_cast<const float4*>(&vs[r][k]);
            acc[r] = fmaf(q.x, w0, acc[r]);
            acc[r] = fmaf(q.y, w1, acc[r]);
            acc[r] = fmaf(q.z, w2, acc[r]);
            acc[r] = fmaf(q.w, w3, acc[r]);
        }
    }
#pragma unroll
    for (int r = 0; r < 8; ++r)
        out[(row0 + r) * NB_D + t] = acc[r];
}

// ---------------------------------------------------------------------------
extern "C" void kernel_launch(void* const* d_in, const int* in_sizes, int n_in,
                              void* d_out, int out_size, void* d_ws, size_t ws_size,
                              hipStream_t stream)
{
    const float* query = (const float*)d_in[0];
    const float* refp  = (const float*)d_in[1];
    const float* value = (const float*)d_in[2];
    // d_in[3] = spatial_shapes (constant, hardcoded)
    const float* Wv = (const float*)d_in[4];
    const float* bv = (const float*)d_in[5];
    const float* Ws = (const float*)d_in[6];
    const float* bs = (const float*)d_in[7];
    const float* Wa = (const float*)d_in[8];
    const float* ba = (const float*)d_in[9];
    const float* Wo = (const float*)d_in[10];
    const float* bo = (const float*)d_in[11];
    float* out = (float*)d_out;

    float* vt  = (float*)d_ws;                                  // B*NH*S*HD
    float* tmp = vt + (size_t)NB_B * NB_NH * NB_S * NB_HD;      // B*Q*D

    hipLaunchKernelGGL(k_vproj,  dim3(NB_B * NB_S / 8), dim3(256), 0, stream,
                       value, Wv, bv, vt);
    hipLaunchKernelGGL(k_sample, dim3(NB_B * NB_Q / 8), dim3(256), 0, stream,
                       query, refp, Ws, bs, Wa, ba, vt, tmp);
    hipLaunchKernelGGL(k_oproj,  dim3(NB_B * NB_Q / 8), dim3(256), 0, stream,
                       tmp, Wo, bo, out);
}

// Round 2
// 282.950 us; speedup vs baseline: 1.3216x; 1.3216x over previous
//
#include <hip/hip_runtime.h>

#define NB_B  2
#define NB_Q  10000
#define NB_D  256
#define NB_NH 8
#define NB_NL 4
#define NB_NP 4
#define NB_HD 32
#define NB_S  21760   // 128*128 + 64*64 + 32*32 + 16*16

// ---------------------------------------------------------------------------
// Kernel 1: v = value @ Wv + bv, stored as vt[b][h][s][hd]  (B,NH,S,HD)
// 16 rows x 256 cols per block; each thread: 4 rows x 4 cols (64 FMA / 4k).
// ---------------------------------------------------------------------------
__global__ __launch_bounds__(256) void k_vproj(const float* __restrict__ value,
                                               const float* __restrict__ Wv,
                                               const float* __restrict__ bv,
                                               float* __restrict__ vt)
{
    __shared__ float qs[16][NB_D];
    const int t = threadIdx.x;
    const int row0 = blockIdx.x * 16;
    {
        const float4* src = reinterpret_cast<const float4*>(value + (size_t)row0 * NB_D);
        float4* dst = reinterpret_cast<float4*>(&qs[0][0]);
#pragma unroll
        for (int i = 0; i < 4; ++i) dst[t + 256 * i] = src[t + 256 * i];
    }
    __syncthreads();

    const int c0 = (t & 63) * 4;
    const int r0 = (t >> 6) * 4;
    float acc[4][4];
    const float4 bias = *reinterpret_cast<const float4*>(&bv[c0]);
#pragma unroll
    for (int r = 0; r < 4; ++r) {
        acc[r][0] = bias.x; acc[r][1] = bias.y; acc[r][2] = bias.z; acc[r][3] = bias.w;
    }

    for (int k = 0; k < NB_D; k += 4) {
        const float4 w0 = *reinterpret_cast<const float4*>(&Wv[(k + 0) * NB_D + c0]);
        const float4 w1 = *reinterpret_cast<const float4*>(&Wv[(k + 1) * NB_D + c0]);
        const float4 w2 = *reinterpret_cast<const float4*>(&Wv[(k + 2) * NB_D + c0]);
        const float4 w3 = *reinterpret_cast<const float4*>(&Wv[(k + 3) * NB_D + c0]);
#pragma unroll
        for (int r = 0; r < 4; ++r) {
            const float4 q = *reinterpret_cast<const float4*>(&qs[r0 + r][k]);
            acc[r][0] = fmaf(q.x, w0.x, acc[r][0]); acc[r][1] = fmaf(q.x, w0.y, acc[r][1]);
            acc[r][2] = fmaf(q.x, w0.z, acc[r][2]); acc[r][3] = fmaf(q.x, w0.w, acc[r][3]);
            acc[r][0] = fmaf(q.y, w1.x, acc[r][0]); acc[r][1] = fmaf(q.y, w1.y, acc[r][1]);
            acc[r][2] = fmaf(q.y, w1.z, acc[r][2]); acc[r][3] = fmaf(q.y, w1.w, acc[r][3]);
            acc[r][0] = fmaf(q.z, w2.x, acc[r][0]); acc[r][1] = fmaf(q.z, w2.y, acc[r][1]);
            acc[r][2] = fmaf(q.z, w2.z, acc[r][2]); acc[r][3] = fmaf(q.z, w2.w, acc[r][3]);
            acc[r][0] = fmaf(q.w, w3.x, acc[r][0]); acc[r][1] = fmaf(q.w, w3.y, acc[r][1]);
            acc[r][2] = fmaf(q.w, w3.z, acc[r][2]); acc[r][3] = fmaf(q.w, w3.w, acc[r][3]);
        }
    }

    const int h = c0 >> 5, hd = c0 & 31;
#pragma unroll
    for (int r = 0; r < 4; ++r) {
        const int row = row0 + r0 + r;
        const int b = row / NB_S;
        const int s = row - b * NB_S;
        float4 o; o.x = acc[r][0]; o.y = acc[r][1]; o.z = acc[r][2]; o.w = acc[r][3];
        *reinterpret_cast<float4*>(&vt[(((size_t)(b * NB_NH + h) * NB_S + s) << 5) + hd]) = o;
    }
}

// ---------------------------------------------------------------------------
// Kernel 2: coords — offsets = q@Ws+bs -> pixel coords; logits = q@Wa+ba ->
// softmax weights. Writes sx, sy, sw  each [B*Q][128]  (si = h*16 + l*4 + p).
// ---------------------------------------------------------------------------
__global__ __launch_bounds__(256) void k_coords(const float* __restrict__ query,
                                                const float* __restrict__ refp,
                                                const float* __restrict__ Ws,
                                                const float* __restrict__ bs,
                                                const float* __restrict__ Wa,
                                                const float* __restrict__ ba,
                                                float* __restrict__ sx,
                                                float* __restrict__ sy,
                                                float* __restrict__ sw)
{
    __shared__ float qs[16][NB_D];
    __shared__ float sl[16][128];
    const int t = threadIdx.x;
    const int row0 = blockIdx.x * 16;
    {
        const float4* src = reinterpret_cast<const float4*>(query + (size_t)row0 * NB_D);
        float4* dst = reinterpret_cast<float4*>(&qs[0][0]);
#pragma unroll
        for (int i = 0; i < 4; ++i) dst[t + 256 * i] = src[t + 256 * i];
    }
    __syncthreads();

    // ---- Part A: sampling offsets (256 cols), 4 rows x 4 cols per thread ----
    {
        const int c0 = (t & 63) * 4;
        const int r0 = (t >> 6) * 4;
        float acc[4][4];
        const float4 bias = *reinterpret_cast<const float4*>(&bs[c0]);
#pragma unroll
        for (int r = 0; r < 4; ++r) {
            acc[r][0] = bias.x; acc[r][1] = bias.y; acc[r][2] = bias.z; acc[r][3] = bias.w;
        }
        for (int k = 0; k < NB_D; k += 4) {
            const float4 w0 = *reinterpret_cast<const float4*>(&Ws[(k + 0) * 256 + c0]);
            const float4 w1 = *reinterpret_cast<const float4*>(&Ws[(k + 1) * 256 + c0]);
            const float4 w2 = *reinterpret_cast<const float4*>(&Ws[(k + 2) * 256 + c0]);
            const float4 w3 = *reinterpret_cast<const float4*>(&Ws[(k + 3) * 256 + c0]);
#pragma unroll
            for (int r = 0; r < 4; ++r) {
                const float4 q = *reinterpret_cast<const float4*>(&qs[r0 + r][k]);
                acc[r][0] = fmaf(q.x, w0.x, acc[r][0]); acc[r][1] = fmaf(q.x, w0.y, acc[r][1]);
                acc[r][2] = fmaf(q.x, w0.z, acc[r][2]); acc[r][3] = fmaf(q.x, w0.w, acc[r][3]);
                acc[r][0] = fmaf(q.y, w1.x, acc[r][0]); acc[r][1] = fmaf(q.y, w1.y, acc[r][1]);
                acc[r][2] = fmaf(q.y, w1.z, acc[r][2]); acc[r][3] = fmaf(q.y, w1.w, acc[r][3]);
                acc[r][0] = fmaf(q.z, w2.x, acc[r][0]); acc[r][1] = fmaf(q.z, w2.y, acc[r][1]);
                acc[r][2] = fmaf(q.z, w2.z, acc[r][2]); acc[r][3] = fmaf(q.z, w2.w, acc[r][3]);
                acc[r][0] = fmaf(q.w, w3.x, acc[r][0]); acc[r][1] = fmaf(q.w, w3.y, acc[r][1]);
                acc[r][2] = fmaf(q.w, w3.z, acc[r][2]); acc[r][3] = fmaf(q.w, w3.w, acc[r][3]);
            }
        }
        // col = ((h*4+l)*4+p)*2 + xy  ->  si = col>>1 = h*16+l*4+p, xy = col&1
        const int si0 = c0 >> 1;
#pragma unroll
        for (int r = 0; r < 4; ++r) {
            const int row = row0 + r0 + r;
#pragma unroll
            for (int cc = 0; cc < 4; ++cc) {
                const int si = si0 + (cc >> 1);
                const int xy = cc & 1;
                const int l = (si >> 2) & 3;
                const float dim = (float)(128 >> l);
                const float ref = refp[((size_t)row * NB_NL + l) * 2 + xy];
                const float coord = ref * dim + acc[r][cc] - 0.5f;
                if (xy == 0) sx[(size_t)row * 128 + si] = coord;
                else         sy[(size_t)row * 128 + si] = coord;
            }
        }
    }

    // ---- Part B: attention logits (128 cols), 2 rows x 4 cols per thread ----
    {
        const int c0 = (t & 31) * 4;
        const int r0 = (t >> 5) * 2;
        float acc[2][4];
        const float4 bias = *reinterpret_cast<const float4*>(&ba[c0]);
#pragma unroll
        for (int r = 0; r < 2; ++r) {
            acc[r][0] = bias.x; acc[r][1] = bias.y; acc[r][2] = bias.z; acc[r][3] = bias.w;
        }
        for (int k = 0; k < NB_D; k += 4) {
            const float4 w0 = *reinterpret_cast<const float4*>(&Wa[(k + 0) * 128 + c0]);
            const float4 w1 = *reinterpret_cast<const float4*>(&Wa[(k + 1) * 128 + c0]);
            const float4 w2 = *reinterpret_cast<const float4*>(&Wa[(k + 2) * 128 + c0]);
            const float4 w3 = *reinterpret_cast<const float4*>(&Wa[(k + 3) * 128 + c0]);
#pragma unroll
            for (int r = 0; r < 2; ++r) {
                const float4 q = *reinterpret_cast<const float4*>(&qs[r0 + r][k]);
                acc[r][0] = fmaf(q.x, w0.x, acc[r][0]); acc[r][1] = fmaf(q.x, w0.y, acc[r][1]);
                acc[r][2] = fmaf(q.x, w0.z, acc[r][2]); acc[r][3] = fmaf(q.x, w0.w, acc[r][3]);
                acc[r][0] = fmaf(q.y, w1.x, acc[r][0]); acc[r][1] = fmaf(q.y, w1.y, acc[r][1]);
                acc[r][2] = fmaf(q.y, w1.z, acc[r][2]); acc[r][3] = fmaf(q.y, w1.w, acc[r][3]);
                acc[r][0] = fmaf(q.z, w2.x, acc[r][0]); acc[r][1] = fmaf(q.z, w2.y, acc[r][1]);
                acc[r][2] = fmaf(q.z, w2.z, acc[r][2]); acc[r][3] = fmaf(q.z, w2.w, acc[r][3]);
                acc[r][0] = fmaf(q.w, w3.x, acc[r][0]); acc[r][1] = fmaf(q.w, w3.y, acc[r][1]);
                acc[r][2] = fmaf(q.w, w3.z, acc[r][2]); acc[r][3] = fmaf(q.w, w3.w, acc[r][3]);
            }
        }
#pragma unroll
        for (int r = 0; r < 2; ++r) {
#pragma unroll
            for (int cc = 0; cc < 4; ++cc) sl[r0 + r][c0 + cc] = acc[r][cc];
        }
    }
    __syncthreads();

    // ---- softmax over 16 per (row, head), write weights ----
    if (t < 128) {
        const int r = t >> 3, h = t & 7;
        const float* pw = &sl[r][h * 16];
        float m = pw[0];
#pragma unroll
        for (int i = 1; i < 16; ++i) m = fmaxf(m, pw[i]);
        float e[16], ssum = 0.f;
#pragma unroll
        for (int i = 0; i < 16; ++i) { e[i] = expf(pw[i] - m); ssum += e[i]; }
        const float inv = 1.f / ssum;
        float* dst = &sw[(size_t)(row0 + r) * 128 + h * 16];
#pragma unroll
        for (int i = 0; i < 16; ++i) dst[i] = e[i] * inv;
    }
}

// ---------------------------------------------------------------------------
// Kernel 3: gather — block = (8 queries, 1 head). Phase 1 precomputes corner
// byte-offsets + folded weights into LDS once; phase 2 does pure load+fma.
// ---------------------------------------------------------------------------
__global__ __launch_bounds__(256) void k_gather(const float* __restrict__ vt,
                                                const float* __restrict__ sx,
                                                const float* __restrict__ sy,
                                                const float* __restrict__ sw,
                                                float* __restrict__ tmp)
{
    __shared__ int   offs[8][16][4];
    __shared__ float wts[8][16][4];
    const int t = threadIdx.x;
    const int row0 = blockIdx.x * 8;
    const int h = blockIdx.y;
    const int b = (row0 >= NB_Q) ? 1 : 0;

    if (t < 128) {
        const int r = t >> 4, s = t & 15;
        const size_t ci = (size_t)(row0 + r) * 128 + h * 16 + s;
        const float x = sx[ci], y = sy[ci], w = sw[ci];
        const int l = s >> 2;
        const int dim = 128 >> l;
        const int startL = (l == 0) ? 0 : (l == 1) ? 16384 : (l == 2) ? 20480 : 21504;
        const float x0f = floorf(x), y0f = floorf(y);
        const float lx = x - x0f, ly = y - y0f;
        const int ix = (int)x0f, iy = (int)y0f;
        const int ix0 = min(max(ix, 0), dim - 1), ix1 = min(max(ix + 1, 0), dim - 1);
        const int iy0 = min(max(iy, 0), dim - 1), iy1 = min(max(iy + 1, 0), dim - 1);
        const float vx0 = (ix >= 0 && ix < dim) ? 1.f : 0.f;
        const float vx1 = (ix + 1 >= 0 && ix + 1 < dim) ? 1.f : 0.f;
        const float vy0 = (iy >= 0 && iy < dim) ? 1.f : 0.f;
        const float vy1 = (iy + 1 >= 0 && iy + 1 < dim) ? 1.f : 0.f;
        offs[r][s][0] = (startL + iy0 * dim + ix0) * (NB_HD * 4);
        offs[r][s][1] = (startL + iy0 * dim + ix1) * (NB_HD * 4);
        offs[r][s][2] = (startL + iy1 * dim + ix0) * (NB_HD * 4);
        offs[r][s][3] = (startL + iy1 * dim + ix1) * (NB_HD * 4);
        wts[r][s][0] = w * (1.f - lx) * (1.f - ly) * vx0 * vy0;
        wts[r][s][1] = w * lx * (1.f - ly) * vx1 * vy0;
        wts[r][s][2] = w * (1.f - lx) * ly * vx0 * vy1;
        wts[r][s][3] = w * lx * ly * vx1 * vy1;
    }
    __syncthreads();

    const int hd = t & 31;
    const int r  = t >> 5;
    const char* slab = reinterpret_cast<const char*>(vt + ((size_t)(b * NB_NH + h) * NB_S) * NB_HD);
    const int hd4 = hd * 4;
    float acc = 0.f;
#pragma unroll
    for (int s = 0; s < 16; ++s) {
        const int4  o  = *reinterpret_cast<const int4*>(&offs[r][s][0]);
        const float4 ww = *reinterpret_cast<const float4*>(&wts[r][s][0]);
        acc = fmaf(ww.x, *reinterpret_cast<const float*>(slab + (o.x + hd4)), acc);
        acc = fmaf(ww.y, *reinterpret_cast<const float*>(slab + (o.y + hd4)), acc);
        acc = fmaf(ww.z, *reinterpret_cast<const float*>(slab + (o.z + hd4)), acc);
        acc = fmaf(ww.w, *reinterpret_cast<const float*>(slab + (o.w + hd4)), acc);
    }
    tmp[(size_t)(row0 + r) * NB_D + h * NB_HD + hd] = acc;
}

// ---------------------------------------------------------------------------
// Kernel 4: out = tmp @ Wo + bo
// ---------------------------------------------------------------------------
__global__ __launch_bounds__(256) void k_oproj(const float* __restrict__ tmp,
                                               const float* __restrict__ Wo,
                                               const float* __restrict__ bo,
                                               float* __restrict__ out)
{
    __shared__ float qs[16][NB_D];
    const int t = threadIdx.x;
    const int row0 = blockIdx.x * 16;
    {
        const float4* src = reinterpret_cast<const float4*>(tmp + (size_t)row0 * NB_D);
        float4* dst = reinterpret_cast<float4*>(&qs[0][0]);
#pragma unroll
        for (int i = 0; i < 4; ++i) dst[t + 256 * i] = src[t + 256 * i];
    }
    __syncthreads();

    const int c0 = (t & 63) * 4;
    const int r0 = (t >> 6) * 4;
    float acc[4][4];
    const float4 bias = *reinterpret_cast<const float4*>(&bo[c0]);
#pragma unroll
    for (int r = 0; r < 4; ++r) {
        acc[r][0] = bias.x; acc[r][1] = bias.y; acc[r][2] = bias.z; acc[r][3] = bias.w;
    }

    for (int k = 0; k < NB_D; k += 4) {
        const float4 w0 = *reinterpret_cast<const float4*>(&Wo[(k + 0) * NB_D + c0]);
        const float4 w1 = *reinterpret_cast<const float4*>(&Wo[(k + 1) * NB_D + c0]);
        const float4 w2 = *reinterpret_cast<const float4*>(&Wo[(k + 2) * NB_D + c0]);
        const float4 w3 = *reinterpret_cast<const float4*>(&Wo[(k + 3) * NB_D + c0]);
#pragma unroll
        for (int r = 0; r < 4; ++r) {
            const float4 q = *reinterpret_cast<const float4*>(&qs[r0 + r][k]);
            acc[r][0] = fmaf(q.x, w0.x, acc[r][0]); acc[r][1] = fmaf(q.x, w0.y, acc[r][1]);
            acc[r][2] = fmaf(q.x, w0.z, acc[r][2]); acc[r][3] = fmaf(q.x, w0.w, acc[r][3]);
            acc[r][0] = fmaf(q.y, w1.x, acc[r][0]); acc[r][1] = fmaf(q.y, w1.y, acc[r][1]);
            acc[r][2] = fmaf(q.y, w1.z, acc[r][2]); acc[r][3] = fmaf(q.y, w1.w, acc[r][3]);
            acc[r][0] = fmaf(q.z, w2.x, acc[r][0]); acc[r][1] = fmaf(q.z, w2.y, acc[r][1]);
            acc[r][2] = fmaf(q.z, w2.z, acc[r][2]); acc[r][3] = fmaf(q.z, w2.w, acc[r][3]);
            acc[r][0] = fmaf(q.w, w3.x, acc[r][0]); acc[r][1] = fmaf(q.w, w3.y, acc[r][1]);
            acc[r][2] = fmaf(q.w, w3.z, acc[r][2]); acc[r][3] = fmaf(q.w, w3.w, acc[r][3]);
        }
    }
#pragma unroll
    for (int r = 0; r < 4; ++r) {
        float4 o; o.x = acc[r][0]; o.y = acc[r][1]; o.z = acc[r][2]; o.w = acc[r][3];
        *reinterpret_cast<float4*>(&out[(size_t)(row0 + r0 + r) * NB_D + c0]) = o;
    }
}

// ---------------------------------------------------------------------------
// Fallback (Plan B): round-0 fused sample kernel (proven correct) — used only
// if ws_size can't hold the coord arrays.
// ---------------------------------------------------------------------------
__global__ __launch_bounds__(256) void k_sample(const float* __restrict__ query,
                                                const float* __restrict__ refp,
                                                const float* __restrict__ Ws,
                                                const float* __restrict__ bs,
                                                const float* __restrict__ Wa,
                                                const float* __restrict__ ba,
                                                const float* __restrict__ vt,
                                                float* __restrict__ tmp)
{
    __shared__ float qs[8][NB_D];
    __shared__ float sxl[8][128];
    __shared__ float syl[8][128];
    __shared__ float swl[8][128];

    const int t = threadIdx.x;
    const int row0 = blockIdx.x * 8;
#pragma unroll
    for (int r = 0; r < 8; ++r)
        qs[r][t] = query[(row0 + r) * NB_D + t];
    __syncthreads();

    {
        float acc[8];
        const float bias = bs[t];
#pragma unroll
        for (int r = 0; r < 8; ++r) acc[r] = bias;
        for (int k = 0; k < NB_D; k += 4) {
            const float w0 = Ws[(k + 0) * 256 + t];
            const float w1 = Ws[(k + 1) * 256 + t];
            const float w2 = Ws[(k + 2) * 256 + t];
            const float w3 = Ws[(k + 3) * 256 + t];
#pragma unroll
            for (int r = 0; r < 8; ++r) {
                const float4 q = *reinterpret_cast<const float4*>(&qs[r][k]);
                acc[r] = fmaf(q.x, w0, acc[r]);
                acc[r] = fmaf(q.y, w1, acc[r]);
                acc[r] = fmaf(q.z, w2, acc[r]);
                acc[r] = fmaf(q.w, w3, acc[r]);
            }
        }
        const int c = t & 1, p = (t >> 1) & 3, l = (t >> 3) & 3, h = t >> 5;
        const float dim = (float)(128 >> l);
        const int si = h * 16 + l * 4 + p;
#pragma unroll
        for (int r = 0; r < 8; ++r) {
            const int row = row0 + r;
            const float rp = refp[(row * NB_NL + l) * 2 + c];
            const float coord = rp * dim + acc[r] - 0.5f;
            if (c == 0) sxl[r][si] = coord;
            else        syl[r][si] = coord;
        }
    }

    {
        const int ta = t & 127;
        const int rb = (t >> 7) * 4;
        float acc[4];
        const float bias = ba[ta];
#pragma unroll
        for (int j = 0; j < 4; ++j) acc[j] = bias;
        for (int k = 0; k < NB_D; k += 4) {
            const float w0 = Wa[(k + 0) * 128 + ta];
            const float w1 = Wa[(k + 1) * 128 + ta];
            const float w2 = Wa[(k + 2) * 128 + ta];
            const float w3 = Wa[(k + 3) * 128 + ta];
#pragma unroll
            for (int j = 0; j < 4; ++j) {
                const float4 q = *reinterpret_cast<const float4*>(&qs[rb + j][k]);
                acc[j] = fmaf(q.x, w0, acc[j]);
                acc[j] = fmaf(q.y, w1, acc[j]);
                acc[j] = fmaf(q.z, w2, acc[j]);
                acc[j] = fmaf(q.w, w3, acc[j]);
            }
        }
#pragma unroll
        for (int j = 0; j < 4; ++j) swl[rb + j][ta] = acc[j];
    }
    __syncthreads();

    if (t < 64) {
        const int r = t >> 3, h = t & 7;
        float* pw = &swl[r][h * 16];
        float m = pw[0];
#pragma unroll
        for (int i = 1; i < 16; ++i) m = fmaxf(m, pw[i]);
        float ssum = 0.f;
#pragma unroll
        for (int i = 0; i < 16; ++i) { const float e = expf(pw[i] - m); pw[i] = e; ssum += e; }
        const float inv = 1.f / ssum;
#pragma unroll
        for (int i = 0; i < 16; ++i) pw[i] *= inv;
    }
    __syncthreads();

    const int lane = t & 63;
    const int wv = t >> 6;
    const int h  = wv * 2 + (lane >> 5);
    const int hd = lane & 31;
    const int b  = row0 / NB_Q;
    const float* vbase = vt + (size_t)(b * NB_NH + h) * (NB_S * NB_HD);
    const int startL[4] = {0, 16384, 20480, 21504};

    for (int r = 0; r < 8; ++r) {
        float acc = 0.f;
#pragma unroll
        for (int l = 0; l < 4; ++l) {
            const int dimL = 128 >> l;
            const float* vlev = vbase + startL[l] * NB_HD + hd;
#pragma unroll
            for (int p = 0; p < 4; ++p) {
                const int si = h * 16 + l * 4 + p;
                const float x = sxl[r][si];
                const float y = syl[r][si];
                const float w = swl[r][si];
                const float x0f = floorf(x), y0f = floorf(y);
                const float lx = x - x0f, ly = y - y0f;
                const int ix = (int)x0f, iy = (int)y0f;
                float v00 = 0.f, v01 = 0.f, v10 = 0.f, v11 = 0.f;
                const bool x0in = (ix >= 0) & (ix < dimL);
                const bool x1in = (ix + 1 >= 0) & (ix + 1 < dimL);
                if ((iy >= 0) & (iy < dimL)) {
                    const float* rp = vlev + (iy * dimL) * NB_HD;
                    if (x0in) v00 = rp[ix * NB_HD];
                    if (x1in) v01 = rp[(ix + 1) * NB_HD];
                }
                if ((iy + 1 >= 0) & (iy + 1 < dimL)) {
                    const float* rp = vlev + ((iy + 1) * dimL) * NB_HD;
                    if (x0in) v10 = rp[ix * NB_HD];
                    if (x1in) v11 = rp[(ix + 1) * NB_HD];
                }
                const float vxy = (v00 * (1.f - lx) + v01 * lx) * (1.f - ly)
                                + (v10 * (1.f - lx) + v11 * lx) * ly;
                acc = fmaf(w, vxy, acc);
            }
        }
        tmp[(row0 + r) * NB_D + h * NB_HD + hd] = acc;
    }
}

// ---------------------------------------------------------------------------
extern "C" void kernel_launch(void* const* d_in, const int* in_sizes, int n_in,
                              void* d_out, int out_size, void* d_ws, size_t ws_size,
                              hipStream_t stream)
{
    const float* query = (const float*)d_in[0];
    const float* refp  = (const float*)d_in[1];
    const float* value = (const float*)d_in[2];
    const float* Wv = (const float*)d_in[4];
    const float* bv = (const float*)d_in[5];
    const float* Ws = (const float*)d_in[6];
    const float* bs = (const float*)d_in[7];
    const float* Wa = (const float*)d_in[8];
    const float* ba = (const float*)d_in[9];
    const float* Wo = (const float*)d_in[10];
    const float* bo = (const float*)d_in[11];
    float* out = (float*)d_out;

    const size_t n_vt  = (size_t)NB_B * NB_NH * NB_S * NB_HD;   // 11,141,120
    const size_t n_tmp = (size_t)NB_B * NB_Q * NB_D;            //  5,120,000
    const size_t n_co  = (size_t)NB_B * NB_Q * 128;             //  2,560,000

    float* vt  = (float*)d_ws;
    float* tmp = vt + n_vt;
    float* sxg = tmp + n_tmp;
    float* syg = sxg + n_co;
    float* swg = syg + n_co;

    const size_t need = (n_vt + n_tmp + 3 * n_co) * sizeof(float);

    hipLaunchKernelGGL(k_vproj, dim3(NB_B * NB_S / 16), dim3(256), 0, stream,
                       value, Wv, bv, vt);

    if (ws_size >= need) {
        hipLaunchKernelGGL(k_coords, dim3(NB_B * NB_Q / 16), dim3(256), 0, stream,
                           query, refp, Ws, bs, Wa, ba, sxg, syg, swg);
        hipLaunchKernelGGL(k_gather, dim3(NB_B * NB_Q / 8, NB_NH), dim3(256), 0, stream,
                           vt, sxg, syg, swg, tmp);
    } else {
        hipLaunchKernelGGL(k_sample, dim3(NB_B * NB_Q / 8), dim3(256), 0, stream,
                           query, refp, Ws, bs, Wa, ba, vt, tmp);
    }

    hipLaunchKernelGGL(k_oproj, dim3(NB_B * NB_Q / 16), dim3(256), 0, stream,
                       tmp, Wo, bo, out);
}

// Round 3
// 232.527 us; speedup vs baseline: 1.6082x; 1.2168x over previous
//
#include <hip/hip_runtime.h>

#define NB_B  2
#define NB_Q  10000
#define NB_D  256
#define NB_NH 8
#define NB_NL 4
#define NB_NP 4
#define NB_HD 32
#define NB_S  21760   // 128*128 + 64*64 + 32*32 + 16*16

__device__ __forceinline__ unsigned bf16rne(float f) {
    unsigned u = __float_as_uint(f);
    return (u + 0x7fffu + ((u >> 16) & 1u)) >> 16;
}

// 4x4 FMA block: acc row A (float[4]) += Q (float4 of k) * w[0..3] (float4 cols)
#define ROWFMA(A, Q) \
    A[0]=fmaf(Q.x,w[0].x,A[0]); A[1]=fmaf(Q.x,w[0].y,A[1]); A[2]=fmaf(Q.x,w[0].z,A[2]); A[3]=fmaf(Q.x,w[0].w,A[3]); \
    A[0]=fmaf(Q.y,w[1].x,A[0]); A[1]=fmaf(Q.y,w[1].y,A[1]); A[2]=fmaf(Q.y,w[1].z,A[2]); A[3]=fmaf(Q.y,w[1].w,A[3]); \
    A[0]=fmaf(Q.z,w[2].x,A[0]); A[1]=fmaf(Q.z,w[2].y,A[1]); A[2]=fmaf(Q.z,w[2].z,A[2]); A[3]=fmaf(Q.z,w[2].w,A[3]); \
    A[0]=fmaf(Q.w,w[3].x,A[0]); A[1]=fmaf(Q.w,w[3].y,A[1]); A[2]=fmaf(Q.w,w[3].z,A[2]); A[3]=fmaf(Q.w,w[3].w,A[3]);

// ---------------------------------------------------------------------------
// Kernel 1: v = value @ Wv + bv -> vt[b][h][s][hd] in BF16.
// 32 rows x 256 cols per block; thread: 8 rows x 4 cols; W double-buffered.
// ---------------------------------------------------------------------------
__global__ __launch_bounds__(256) void k_vproj(const float* __restrict__ value,
                                               const float* __restrict__ Wv,
                                               const float* __restrict__ bv,
                                               unsigned short* __restrict__ vt)
{
    __shared__ float qs[32][NB_D];
    const int t = threadIdx.x;
    const int row0 = blockIdx.x * 32;
    {
        const float4* src = reinterpret_cast<const float4*>(value + (size_t)row0 * NB_D);
        float4* dst = reinterpret_cast<float4*>(&qs[0][0]);
#pragma unroll
        for (int i = 0; i < 8; ++i) dst[t + 256 * i] = src[t + 256 * i];
    }
    __syncthreads();

    const int c0 = (t & 63) * 4;
    const int r0 = (t >> 6) * 8;
    float acc[8][4];
    const float4 bias = *reinterpret_cast<const float4*>(bv + c0);
#pragma unroll
    for (int r = 0; r < 8; ++r) { acc[r][0]=bias.x; acc[r][1]=bias.y; acc[r][2]=bias.z; acc[r][3]=bias.w; }

    const float* wp = Wv + c0;
    float4 w[4], wn[4];
#pragma unroll
    for (int j = 0; j < 4; ++j) w[j] = *reinterpret_cast<const float4*>(wp + j * NB_D);

    for (int k = 0; k < NB_D - 4; k += 4) {
#pragma unroll
        for (int j = 0; j < 4; ++j) wn[j] = *reinterpret_cast<const float4*>(wp + (k + 4 + j) * NB_D);
#pragma unroll
        for (int r = 0; r < 8; ++r) {
            const float4 q = *reinterpret_cast<const float4*>(&qs[r0 + r][k]);
            ROWFMA(acc[r], q)
        }
#pragma unroll
        for (int j = 0; j < 4; ++j) w[j] = wn[j];
    }
    {
        const int k = NB_D - 4;
#pragma unroll
        for (int r = 0; r < 8; ++r) {
            const float4 q = *reinterpret_cast<const float4*>(&qs[r0 + r][k]);
            ROWFMA(acc[r], q)
        }
    }

    const int h = c0 >> 5, hd = c0 & 31;
    const int b = (row0 >= NB_S) ? 1 : 0;            // block-uniform
    const int sbase = row0 - b * NB_S + r0;
#pragma unroll
    for (int r = 0; r < 8; ++r) {
        const size_t idx = ((size_t)((b * NB_NH + h) * NB_S + (sbase + r)) << 5) + hd;
        uint2 o;
        o.x = bf16rne(acc[r][0]) | (bf16rne(acc[r][1]) << 16);
        o.y = bf16rne(acc[r][2]) | (bf16rne(acc[r][3]) << 16);
        *reinterpret_cast<uint2*>(reinterpret_cast<char*>(vt) + idx * 2) = o;
    }
}

// ---------------------------------------------------------------------------
// Kernel 2: coords — offsets (q@Ws+bs) -> pixel coords; logits (q@Wa+ba) ->
// softmax weights. Block = 32 queries. Writes sx, sy, sw [B*Q][128].
// ---------------------------------------------------------------------------
__global__ __launch_bounds__(256) void k_coords(const float* __restrict__ query,
                                                const float* __restrict__ refp,
                                                const float* __restrict__ Ws,
                                                const float* __restrict__ bs,
                                                const float* __restrict__ Wa,
                                                const float* __restrict__ ba,
                                                float* __restrict__ sx,
                                                float* __restrict__ sy,
                                                float* __restrict__ sw)
{
    __shared__ float qs[32][NB_D];
    __shared__ float sl[32][132];   // padded: breaks 32-way bank aliasing in softmax
    const int t = threadIdx.x;
    const int row0 = blockIdx.x * 32;
    {
        const float4* src = reinterpret_cast<const float4*>(query + (size_t)row0 * NB_D);
        float4* dst = reinterpret_cast<float4*>(&qs[0][0]);
#pragma unroll
        for (int i = 0; i < 8; ++i) dst[t + 256 * i] = src[t + 256 * i];
    }
    __syncthreads();

    // ---- Part A: sampling offsets (256 cols), thread: 8 rows x 4 cols ----
    {
        const int c0 = (t & 63) * 4;
        const int r0 = (t >> 6) * 8;
        float acc[8][4];
        const float4 bias = *reinterpret_cast<const float4*>(bs + c0);
#pragma unroll
        for (int r = 0; r < 8; ++r) { acc[r][0]=bias.x; acc[r][1]=bias.y; acc[r][2]=bias.z; acc[r][3]=bias.w; }

        const float* wp = Ws + c0;
        float4 w[4], wn[4];
#pragma unroll
        for (int j = 0; j < 4; ++j) w[j] = *reinterpret_cast<const float4*>(wp + j * 256);
        for (int k = 0; k < NB_D - 4; k += 4) {
#pragma unroll
            for (int j = 0; j < 4; ++j) wn[j] = *reinterpret_cast<const float4*>(wp + (k + 4 + j) * 256);
#pragma unroll
            for (int r = 0; r < 8; ++r) {
                const float4 q = *reinterpret_cast<const float4*>(&qs[r0 + r][k]);
                ROWFMA(acc[r], q)
            }
#pragma unroll
            for (int j = 0; j < 4; ++j) w[j] = wn[j];
        }
        {
            const int k = NB_D - 4;
#pragma unroll
            for (int r = 0; r < 8; ++r) {
                const float4 q = *reinterpret_cast<const float4*>(&qs[r0 + r][k]);
                ROWFMA(acc[r], q)
            }
        }

        // col = ((h*4+l)*4+p)*2 + xy -> si = col>>1 = h*16+l*4+p
        const int si0 = c0 >> 1;
#pragma unroll
        for (int r = 0; r < 8; ++r) {
            const int row = row0 + r0 + r;
#pragma unroll
            for (int cc = 0; cc < 4; ++cc) {
                const int si = si0 + (cc >> 1);
                const int xy = cc & 1;
                const int l = (si >> 2) & 3;
                const float dim = (float)(128 >> l);
                const float ref = refp[((size_t)row * NB_NL + l) * 2 + xy];
                const float coord = ref * dim + acc[r][cc] - 0.5f;
                if (xy == 0) sx[(size_t)row * 128 + si] = coord;
                else         sy[(size_t)row * 128 + si] = coord;
            }
        }
    }

    // ---- Part B: attention logits (128 cols), thread: 4 rows x 4 cols ----
    {
        const int c0 = (t & 31) * 4;
        const int r0 = (t >> 5) * 4;
        float acc[4][4];
        const float4 bias = *reinterpret_cast<const float4*>(ba + c0);
#pragma unroll
        for (int r = 0; r < 4; ++r) { acc[r][0]=bias.x; acc[r][1]=bias.y; acc[r][2]=bias.z; acc[r][3]=bias.w; }

        const float* wp = Wa + c0;
        float4 w[4], wn[4];
#pragma unroll
        for (int j = 0; j < 4; ++j) w[j] = *reinterpret_cast<const float4*>(wp + j * 128);
        for (int k = 0; k < NB_D - 4; k += 4) {
#pragma unroll
            for (int j = 0; j < 4; ++j) wn[j] = *reinterpret_cast<const float4*>(wp + (k + 4 + j) * 128);
#pragma unroll
            for (int r = 0; r < 4; ++r) {
                const float4 q = *reinterpret_cast<const float4*>(&qs[r0 + r][k]);
                ROWFMA(acc[r], q)
            }
#pragma unroll
            for (int j = 0; j < 4; ++j) w[j] = wn[j];
        }
        {
            const int k = NB_D - 4;
#pragma unroll
            for (int r = 0; r < 4; ++r) {
                const float4 q = *reinterpret_cast<const float4*>(&qs[r0 + r][k]);
                ROWFMA(acc[r], q)
            }
        }
#pragma unroll
        for (int r = 0; r < 4; ++r)
#pragma unroll
            for (int cc = 0; cc < 4; ++cc) sl[r0 + r][c0 + cc] = acc[r][cc];
    }
    __syncthreads();

    // ---- softmax over 16 per (row, head): 256 threads = 32 rows x 8 heads ----
    {
        const int r = t >> 3, h = t & 7;
        const float* pw = &sl[r][h * 16];
        float m = pw[0];
#pragma unroll
        for (int i = 1; i < 16; ++i) m = fmaxf(m, pw[i]);
        float e[16], ssum = 0.f;
#pragma unroll
        for (int i = 0; i < 16; ++i) { e[i] = expf(pw[i] - m); ssum += e[i]; }
        const float inv = 1.f / ssum;
        float* dst = &sw[(size_t)(row0 + r) * 128 + h * 16];
#pragma unroll
        for (int i = 0; i < 16; ++i) dst[i] = e[i] * inv;
    }
}

// ---------------------------------------------------------------------------
// Kernel 3: gather — block = (16 queries, 1 head); 1-D grid, head = id & 7 so
// round-robin XCD dispatch keeps one head's slab per XCD (L2 locality).
// Phase 1: 256 threads compute corner byte-offsets + folded weights -> LDS.
// Phase 2: thread = (query, hd-pair), packed bf16x2 loads, pure load+fma.
// ---------------------------------------------------------------------------
__global__ __launch_bounds__(256) void k_gather(const unsigned short* __restrict__ vt,
                                                const float* __restrict__ sx,
                                                const float* __restrict__ sy,
                                                const float* __restrict__ sw,
                                                float* __restrict__ tmp)
{
    __shared__ int   offs[16][16][4];
    __shared__ float wts[16][16][4];
    const int t = threadIdx.x;
    const int gid = blockIdx.x;
    const int h = gid & 7;
    const int row0 = (gid >> 3) * 16;
    const int b = (row0 >= NB_Q) ? 1 : 0;

    {
        const int r = t >> 4, s = t & 15;
        const size_t ci = (size_t)(row0 + r) * 128 + h * 16 + s;
        const float x = sx[ci], y = sy[ci], w = sw[ci];
        const int l = s >> 2;
        const int dim = 128 >> l;
        const int startL = (l == 0) ? 0 : (l == 1) ? 16384 : (l == 2) ? 20480 : 21504;
        const float x0f = floorf(x), y0f = floorf(y);
        const float lx = x - x0f, ly = y - y0f;
        const int ix = (int)x0f, iy = (int)y0f;
        const int ix0 = min(max(ix, 0), dim - 1), ix1 = min(max(ix + 1, 0), dim - 1);
        const int iy0 = min(max(iy, 0), dim - 1), iy1 = min(max(iy + 1, 0), dim - 1);
        const float vx0 = (ix >= 0 && ix < dim) ? 1.f : 0.f;
        const float vx1 = (ix + 1 >= 0 && ix + 1 < dim) ? 1.f : 0.f;
        const float vy0 = (iy >= 0 && iy < dim) ? 1.f : 0.f;
        const float vy1 = (iy + 1 >= 0 && iy + 1 < dim) ? 1.f : 0.f;
        offs[r][s][0] = (startL + iy0 * dim + ix0) * (NB_HD * 2);   // byte offsets (bf16)
        offs[r][s][1] = (startL + iy0 * dim + ix1) * (NB_HD * 2);
        offs[r][s][2] = (startL + iy1 * dim + ix0) * (NB_HD * 2);
        offs[r][s][3] = (startL + iy1 * dim + ix1) * (NB_HD * 2);
        wts[r][s][0] = w * (1.f - lx) * (1.f - ly) * vx0 * vy0;
        wts[r][s][1] = w * lx * (1.f - ly) * vx1 * vy0;
        wts[r][s][2] = w * (1.f - lx) * ly * vx0 * vy1;
        wts[r][s][3] = w * lx * ly * vx1 * vy1;
    }
    __syncthreads();

    const int r = t >> 4, hd2 = t & 15;
    const char* slab = reinterpret_cast<const char*>(vt)
                     + (size_t)(b * NB_NH + h) * NB_S * (NB_HD * 2);
    const int byo = hd2 * 4;
    float ax = 0.f, ay = 0.f;
#pragma unroll
    for (int s = 0; s < 16; ++s) {
        const int4   o = *reinterpret_cast<const int4*>(&offs[r][s][0]);
        const float4 w = *reinterpret_cast<const float4*>(&wts[r][s][0]);
        const unsigned u0 = *reinterpret_cast<const unsigned*>(slab + (o.x + byo));
        const unsigned u1 = *reinterpret_cast<const unsigned*>(slab + (o.y + byo));
        const unsigned u2 = *reinterpret_cast<const unsigned*>(slab + (o.z + byo));
        const unsigned u3 = *reinterpret_cast<const unsigned*>(slab + (o.w + byo));
        ax = fmaf(w.x, __uint_as_float(u0 << 16), ax);
        ay = fmaf(w.x, __uint_as_float(u0 & 0xffff0000u), ay);
        ax = fmaf(w.y, __uint_as_float(u1 << 16), ax);
        ay = fmaf(w.y, __uint_as_float(u1 & 0xffff0000u), ay);
        ax = fmaf(w.z, __uint_as_float(u2 << 16), ax);
        ay = fmaf(w.z, __uint_as_float(u2 & 0xffff0000u), ay);
        ax = fmaf(w.w, __uint_as_float(u3 << 16), ax);
        ay = fmaf(w.w, __uint_as_float(u3 & 0xffff0000u), ay);
    }
    float2 o2; o2.x = ax; o2.y = ay;
    *reinterpret_cast<float2*>(tmp + (size_t)(row0 + r) * NB_D + h * NB_HD + hd2 * 2) = o2;
}

// ---------------------------------------------------------------------------
// Kernel 4: out = tmp @ Wo + bo. Same structure as k_vproj, fp32 out.
// ---------------------------------------------------------------------------
__global__ __launch_bounds__(256) void k_oproj(const float* __restrict__ tmp,
                                               const float* __restrict__ Wo,
                                               const float* __restrict__ bo,
                                               float* __restrict__ out)
{
    __shared__ float qs[32][NB_D];
    const int t = threadIdx.x;
    const int row0 = blockIdx.x * 32;
    {
        const float4* src = reinterpret_cast<const float4*>(tmp + (size_t)row0 * NB_D);
        float4* dst = reinterpret_cast<float4*>(&qs[0][0]);
#pragma unroll
        for (int i = 0; i < 8; ++i) dst[t + 256 * i] = src[t + 256 * i];
    }
    __syncthreads();

    const int c0 = (t & 63) * 4;
    const int r0 = (t >> 6) * 8;
    float acc[8][4];
    const float4 bias = *reinterpret_cast<const float4*>(bo + c0);
#pragma unroll
    for (int r = 0; r < 8; ++r) { acc[r][0]=bias.x; acc[r][1]=bias.y; acc[r][2]=bias.z; acc[r][3]=bias.w; }

    const float* wp = Wo + c0;
    float4 w[4], wn[4];
#pragma unroll
    for (int j = 0; j < 4; ++j) w[j] = *reinterpret_cast<const float4*>(wp + j * NB_D);
    for (int k = 0; k < NB_D - 4; k += 4) {
#pragma unroll
        for (int j = 0; j < 4; ++j) wn[j] = *reinterpret_cast<const float4*>(wp + (k + 4 + j) * NB_D);
#pragma unroll
        for (int r = 0; r < 8; ++r) {
            const float4 q = *reinterpret_cast<const float4*>(&qs[r0 + r][k]);
            ROWFMA(acc[r], q)
        }
#pragma unroll
        for (int j = 0; j < 4; ++j) w[j] = wn[j];
    }
    {
        const int k = NB_D - 4;
#pragma unroll
        for (int r = 0; r < 8; ++r) {
            const float4 q = *reinterpret_cast<const float4*>(&qs[r0 + r][k]);
            ROWFMA(acc[r], q)
        }
    }
#pragma unroll
    for (int r = 0; r < 8; ++r) {
        float4 o; o.x = acc[r][0]; o.y = acc[r][1]; o.z = acc[r][2]; o.w = acc[r][3];
        *reinterpret_cast<float4*>(out + (size_t)(row0 + r0 + r) * NB_D + c0) = o;
    }
}

// ---------------------------------------------------------------------------
extern "C" void kernel_launch(void* const* d_in, const int* in_sizes, int n_in,
                              void* d_out, int out_size, void* d_ws, size_t ws_size,
                              hipStream_t stream)
{
    const float* query = (const float*)d_in[0];
    const float* refp  = (const float*)d_in[1];
    const float* value = (const float*)d_in[2];
    const float* Wv = (const float*)d_in[4];
    const float* bv = (const float*)d_in[5];
    const float* Ws = (const float*)d_in[6];
    const float* bs = (const float*)d_in[7];
    const float* Wa = (const float*)d_in[8];
    const float* ba = (const float*)d_in[9];
    const float* Wo = (const float*)d_in[10];
    const float* bo = (const float*)d_in[11];
    float* out = (float*)d_out;

    const size_t n_vt  = (size_t)NB_B * NB_NH * NB_S * NB_HD;   // 11,141,120 (bf16)
    const size_t n_tmp = (size_t)NB_B * NB_Q * NB_D;            //  5,120,000
    const size_t n_co  = (size_t)NB_B * NB_Q * 128;             //  2,560,000

    unsigned short* vt = (unsigned short*)d_ws;
    float* tmp = (float*)((char*)d_ws + n_vt * sizeof(unsigned short));
    float* sxg = tmp + n_tmp;
    float* syg = sxg + n_co;
    float* swg = syg + n_co;

    hipLaunchKernelGGL(k_vproj, dim3(NB_B * NB_S / 32), dim3(256), 0, stream,
                       value, Wv, bv, vt);
    hipLaunchKernelGGL(k_coords, dim3(NB_B * NB_Q / 32), dim3(256), 0, stream,
                       query, refp, Ws, bs, Wa, ba, sxg, syg, swg);
    hipLaunchKernelGGL(k_gather, dim3(NB_B * NB_Q / 16 * NB_NH), dim3(256), 0, stream,
                       vt, sxg, syg, swg, tmp);
    hipLaunchKernelGGL(k_oproj, dim3(NB_B * NB_Q / 32), dim3(256), 0, stream,
                       tmp, Wo, bo, out);
}

// Round 4
// 171.408 us; speedup vs baseline: 2.1817x; 1.3566x over previous
//
#include <hip/hip_runtime.h>

#define NB_B  2
#define NB_Q  10000
#define NB_D  256
#define NB_NH 8
#define NB_NL 4
#define NB_NP 4
#define NB_HD 32
#define NB_S  21760   // 128*128 + 64*64 + 32*32 + 16*16
#define MQ_PAD 20032  // 20000 padded to 64

typedef _Float16 half8 __attribute__((ext_vector_type(8)));
typedef float f32x4 __attribute__((ext_vector_type(4)));

// ---------------------------------------------------------------------------
// Prep: transpose + fp16-convert weights.
// Concatenated column space: [0,256)=Wv, [256,640)=Ws|Wa, [640,896)=Wo.
// Output layouts: Wt[n][k] fp16, k-major (256 k each).
// ---------------------------------------------------------------------------
__global__ __launch_bounds__(256) void k_prepw(const float* __restrict__ Wv,
                                               const float* __restrict__ Ws,
                                               const float* __restrict__ Wa,
                                               const float* __restrict__ Wo,
                                               _Float16* __restrict__ Wvt,
                                               _Float16* __restrict__ Wsat,
                                               _Float16* __restrict__ Wot)
{
    const int k = threadIdx.x;
    const int nc = blockIdx.x;
    if (nc < 256) {
        Wvt[nc * 256 + k] = (_Float16)Wv[k * 256 + nc];
    } else if (nc < 640) {
        const int n = nc - 256;
        const float v = (n < 256) ? Ws[k * 256 + n] : Wa[k * 128 + (n - 256)];
        Wsat[n * 256 + k] = (_Float16)v;
    } else {
        const int n = nc - 640;
        Wot[n * 256 + k] = (_Float16)Wo[k * 256 + n];
    }
}

// ---------------------------------------------------------------------------
// GEMM 1: v = value @ Wv (+bv in epilogue) -> vt[b][h][s][hd] fp16.
// BM=64, BN=256, BK=32. 4 waves; wave w: cols [w*64, w*64+64). 16 MFMA/K-step.
// ---------------------------------------------------------------------------
__global__ __launch_bounds__(256) void k_vproj_mm(const float* __restrict__ value,
                                                  const _Float16* __restrict__ Wvt,
                                                  const float* __restrict__ bv,
                                                  _Float16* __restrict__ vt)
{
    __shared__ _Float16 Alds[4 * 64 * 8];    // [kb][row][8k]  4 KB
    __shared__ _Float16 Blds[4 * 256 * 8];   // [kb][n][8k]   16 KB
    const int t = threadIdx.x;
    const int lane = t & 63, w = t >> 6;
    const int row0 = blockIdx.x * 64;

    const int srow = t & 63, skq = t >> 6;           // A staging: row, k-oct
    const float* Abase = value + (size_t)(row0 + srow) * 256 + skq * 8;
    const uint4* Bbase = reinterpret_cast<const uint4*>(Wvt + (size_t)t * 256);

    float4 a0 = *reinterpret_cast<const float4*>(Abase);
    float4 a1 = *reinterpret_cast<const float4*>(Abase + 4);
    uint4 br[4];
#pragma unroll
    for (int i = 0; i < 4; ++i) br[i] = Bbase[i];

    f32x4 acc[4][4];
#pragma unroll
    for (int fr = 0; fr < 4; ++fr)
#pragma unroll
        for (int fc = 0; fc < 4; ++fc) acc[fr][fc] = (f32x4){0.f, 0.f, 0.f, 0.f};

    for (int kt = 0; kt < 8; ++kt) {
        half8 av;
        av[0] = (_Float16)a0.x; av[1] = (_Float16)a0.y; av[2] = (_Float16)a0.z; av[3] = (_Float16)a0.w;
        av[4] = (_Float16)a1.x; av[5] = (_Float16)a1.y; av[6] = (_Float16)a1.z; av[7] = (_Float16)a1.w;
        *reinterpret_cast<half8*>(&Alds[(skq * 64 + srow) * 8]) = av;
#pragma unroll
        for (int i = 0; i < 4; ++i)
            *reinterpret_cast<uint4*>(&Blds[(i * 256 + t) * 8]) = br[i];
        if (kt < 7) {
            const int k0n = (kt + 1) * 32;
            a0 = *reinterpret_cast<const float4*>(Abase + k0n);
            a1 = *reinterpret_cast<const float4*>(Abase + k0n + 4);
#pragma unroll
            for (int i = 0; i < 4; ++i) br[i] = Bbase[(kt + 1) * 4 + i];
        }
        __syncthreads();
        half8 af[4], bf[4];
#pragma unroll
        for (int fr = 0; fr < 4; ++fr)
            af[fr] = *reinterpret_cast<const half8*>(&Alds[(((lane >> 4) * 64) + fr * 16 + (lane & 15)) * 8]);
#pragma unroll
        for (int fc = 0; fc < 4; ++fc)
            bf[fc] = *reinterpret_cast<const half8*>(&Blds[(((lane >> 4) * 256) + w * 64 + fc * 16 + (lane & 15)) * 8]);
#pragma unroll
        for (int fr = 0; fr < 4; ++fr)
#pragma unroll
            for (int fc = 0; fc < 4; ++fc)
                acc[fr][fc] = __builtin_amdgcn_mfma_f32_16x16x32_f16(af[fr], bf[fc], acc[fr][fc], 0, 0, 0);
        __syncthreads();
    }

    const int b = (row0 >= NB_S) ? 1 : 0;
    const int sb = row0 - b * NB_S;
#pragma unroll
    for (int fc = 0; fc < 4; ++fc) {
        const int n = w * 64 + fc * 16 + (lane & 15);
        const int h = n >> 5, hd = n & 31;
        const float bvn = bv[n];
#pragma unroll
        for (int fr = 0; fr < 4; ++fr) {
            const f32x4 c = acc[fr][fc];
#pragma unroll
            for (int j = 0; j < 4; ++j) {
                const int m = fr * 16 + (lane >> 4) * 4 + j;
                vt[((size_t)((b * NB_NH + h) * NB_S + (sb + m)) << 5) + hd] = (_Float16)(c[j] + bvn);
            }
        }
    }
}

// ---------------------------------------------------------------------------
// GEMM 2: lin = query @ [Ws|Wa]  (20032x384, no bias). BM=64, BN=384, BK=32.
// Wave w: cols [w*96, w*96+96). 24 MFMA/K-step. A rows guarded (<20000).
// ---------------------------------------------------------------------------
__global__ __launch_bounds__(256) void k_coords_mm(const float* __restrict__ query,
                                                   const _Float16* __restrict__ Wsat,
                                                   float* __restrict__ lin)
{
    __shared__ _Float16 Alds[4 * 64 * 8];    //  4 KB
    __shared__ _Float16 Blds[4 * 384 * 8];   // 24 KB
    const int t = threadIdx.x;
    const int lane = t & 63, w = t >> 6;
    const int row0 = blockIdx.x * 64;

    const int srow = t & 63, skq = t >> 6;
    const bool aok = (row0 + srow) < 20000;
    const float* Abase = query + (size_t)(row0 + srow) * 256 + skq * 8;

    float4 a0, a1;
    if (aok) { a0 = *reinterpret_cast<const float4*>(Abase); a1 = *reinterpret_cast<const float4*>(Abase + 4); }
    else     { a0 = float4{0,0,0,0}; a1 = float4{0,0,0,0}; }
    uint4 br[6];
#pragma unroll
    for (int i = 0; i < 6; ++i) {
        const int idx = i * 256 + t;
        const int kb = (idx >= 1152) ? 3 : (idx >= 768) ? 2 : (idx >= 384) ? 1 : 0;
        const int n = idx - kb * 384;
        br[i] = *reinterpret_cast<const uint4*>(Wsat + (size_t)n * 256 + kb * 8);
    }

    f32x4 acc[4][6];
#pragma unroll
    for (int fr = 0; fr < 4; ++fr)
#pragma unroll
        for (int fc = 0; fc < 6; ++fc) acc[fr][fc] = (f32x4){0.f, 0.f, 0.f, 0.f};

    for (int kt = 0; kt < 8; ++kt) {
        half8 av;
        av[0] = (_Float16)a0.x; av[1] = (_Float16)a0.y; av[2] = (_Float16)a0.z; av[3] = (_Float16)a0.w;
        av[4] = (_Float16)a1.x; av[5] = (_Float16)a1.y; av[6] = (_Float16)a1.z; av[7] = (_Float16)a1.w;
        *reinterpret_cast<half8*>(&Alds[(skq * 64 + srow) * 8]) = av;
#pragma unroll
        for (int i = 0; i < 6; ++i) {
            const int idx = i * 256 + t;
            *reinterpret_cast<uint4*>(&Blds[idx * 8]) = br[i];
        }
        if (kt < 7) {
            const int k0n = (kt + 1) * 32;
            if (aok) { a0 = *reinterpret_cast<const float4*>(Abase + k0n); a1 = *reinterpret_cast<const float4*>(Abase + k0n + 4); }
#pragma unroll
            for (int i = 0; i < 6; ++i) {
                const int idx = i * 256 + t;
                const int kb = (idx >= 1152) ? 3 : (idx >= 768) ? 2 : (idx >= 384) ? 1 : 0;
                const int n = idx - kb * 384;
                br[i] = *reinterpret_cast<const uint4*>(Wsat + (size_t)n * 256 + k0n + kb * 8);
            }
        }
        __syncthreads();
        half8 af[4], bf[6];
#pragma unroll
        for (int fr = 0; fr < 4; ++fr)
            af[fr] = *reinterpret_cast<const half8*>(&Alds[(((lane >> 4) * 64) + fr * 16 + (lane & 15)) * 8]);
#pragma unroll
        for (int fc = 0; fc < 6; ++fc)
            bf[fc] = *reinterpret_cast<const half8*>(&Blds[(((lane >> 4) * 384) + w * 96 + fc * 16 + (lane & 15)) * 8]);
#pragma unroll
        for (int fr = 0; fr < 4; ++fr)
#pragma unroll
            for (int fc = 0; fc < 6; ++fc)
                acc[fr][fc] = __builtin_amdgcn_mfma_f32_16x16x32_f16(af[fr], bf[fc], acc[fr][fc], 0, 0, 0);
        __syncthreads();
    }

#pragma unroll
    for (int fc = 0; fc < 6; ++fc) {
        const int n = w * 96 + fc * 16 + (lane & 15);
#pragma unroll
        for (int fr = 0; fr < 4; ++fr) {
            const f32x4 c = acc[fr][fc];
#pragma unroll
            for (int j = 0; j < 4; ++j) {
                const int m = fr * 16 + (lane >> 4) * 4 + j;
                lin[(size_t)(row0 + m) * 384 + n] = c[j];
            }
        }
    }
}

// ---------------------------------------------------------------------------
// coords postprocess: bias + softmax + pixel coords. Block = 2 rows x 128 si.
// ---------------------------------------------------------------------------
__global__ __launch_bounds__(256) void k_cpost(const float* __restrict__ lin,
                                               const float* __restrict__ refp,
                                               const float* __restrict__ bs,
                                               const float* __restrict__ ba,
                                               float* __restrict__ sx,
                                               float* __restrict__ sy,
                                               float* __restrict__ sw)
{
    __shared__ float eg[2][128];
    const int t = threadIdx.x;
    const int r = t >> 7, si = t & 127;
    const int row = blockIdx.x * 2 + r;
    const float lg = lin[(size_t)row * 384 + 256 + si] + ba[si];
    eg[r][si] = lg;
    __syncthreads();
    const int h0 = si & 0x70;
    float m = eg[r][h0];
#pragma unroll
    for (int i = 1; i < 16; ++i) m = fmaxf(m, eg[r][h0 + i]);
    __syncthreads();
    const float e = expf(lg - m);
    eg[r][si] = e;
    __syncthreads();
    float ssum = 0.f;
#pragma unroll
    for (int i = 0; i < 16; ++i) ssum += eg[r][h0 + i];
    sw[(size_t)row * 128 + si] = e / ssum;

    const int l = (si >> 2) & 3;
    const float dim = (float)(128 >> l);
    const float ox = lin[(size_t)row * 384 + si * 2]     + bs[si * 2];
    const float oy = lin[(size_t)row * 384 + si * 2 + 1] + bs[si * 2 + 1];
    const float rx = refp[((size_t)row * 4 + l) * 2];
    const float ry = refp[((size_t)row * 4 + l) * 2 + 1];
    sx[(size_t)row * 128 + si] = rx * dim + ox - 0.5f;
    sy[(size_t)row * 128 + si] = ry * dim + oy - 0.5f;
}

// ---------------------------------------------------------------------------
// gather: block = (16 queries, 1 head); head = blockIdx.x & 7 (XCD locality).
// vt fp16; writes tmp fp16.
// ---------------------------------------------------------------------------
__global__ __launch_bounds__(256) void k_gather(const _Float16* __restrict__ vt,
                                                const float* __restrict__ sx,
                                                const float* __restrict__ sy,
                                                const float* __restrict__ sw,
                                                _Float16* __restrict__ tmp)
{
    __shared__ int   offs[16][16][4];
    __shared__ float wts[16][16][4];
    const int t = threadIdx.x;
    const int gid = blockIdx.x;
    const int h = gid & 7;
    const int row0 = (gid >> 3) * 16;
    const int b = (row0 >= NB_Q) ? 1 : 0;

    {
        const int r = t >> 4, s = t & 15;
        const size_t ci = (size_t)(row0 + r) * 128 + h * 16 + s;
        const float x = sx[ci], y = sy[ci], w = sw[ci];
        const int l = s >> 2;
        const int dim = 128 >> l;
        const int startL = (l == 0) ? 0 : (l == 1) ? 16384 : (l == 2) ? 20480 : 21504;
        const float x0f = floorf(x), y0f = floorf(y);
        const float lx = x - x0f, ly = y - y0f;
        const int ix = (int)x0f, iy = (int)y0f;
        const int ix0 = min(max(ix, 0), dim - 1), ix1 = min(max(ix + 1, 0), dim - 1);
        const int iy0 = min(max(iy, 0), dim - 1), iy1 = min(max(iy + 1, 0), dim - 1);
        const float vx0 = (ix >= 0 && ix < dim) ? 1.f : 0.f;
        const float vx1 = (ix + 1 >= 0 && ix + 1 < dim) ? 1.f : 0.f;
        const float vy0 = (iy >= 0 && iy < dim) ? 1.f : 0.f;
        const float vy1 = (iy + 1 >= 0 && iy + 1 < dim) ? 1.f : 0.f;
        offs[r][s][0] = (startL + iy0 * dim + ix0) * (NB_HD * 2);
        offs[r][s][1] = (startL + iy0 * dim + ix1) * (NB_HD * 2);
        offs[r][s][2] = (startL + iy1 * dim + ix0) * (NB_HD * 2);
        offs[r][s][3] = (startL + iy1 * dim + ix1) * (NB_HD * 2);
        wts[r][s][0] = w * (1.f - lx) * (1.f - ly) * vx0 * vy0;
        wts[r][s][1] = w * lx * (1.f - ly) * vx1 * vy0;
        wts[r][s][2] = w * (1.f - lx) * ly * vx0 * vy1;
        wts[r][s][3] = w * lx * ly * vx1 * vy1;
    }
    __syncthreads();

    const int r = t >> 4, hd2 = t & 15;
    const char* slab = reinterpret_cast<const char*>(vt)
                     + (size_t)(b * NB_NH + h) * NB_S * (NB_HD * 2);
    const int byo = hd2 * 4;
    float ax = 0.f, ay = 0.f;
#pragma unroll
    for (int s = 0; s < 16; ++s) {
        const int4   o = *reinterpret_cast<const int4*>(&offs[r][s][0]);
        const float4 w = *reinterpret_cast<const float4*>(&wts[r][s][0]);
        union { unsigned u; _Float16 h[2]; } c0, c1, c2, c3;
        c0.u = *reinterpret_cast<const unsigned*>(slab + (o.x + byo));
        c1.u = *reinterpret_cast<const unsigned*>(slab + (o.y + byo));
        c2.u = *reinterpret_cast<const unsigned*>(slab + (o.z + byo));
        c3.u = *reinterpret_cast<const unsigned*>(slab + (o.w + byo));
        ax = fmaf(w.x, (float)c0.h[0], ax); ay = fmaf(w.x, (float)c0.h[1], ay);
        ax = fmaf(w.y, (float)c1.h[0], ax); ay = fmaf(w.y, (float)c1.h[1], ay);
        ax = fmaf(w.z, (float)c2.h[0], ax); ay = fmaf(w.z, (float)c2.h[1], ay);
        ax = fmaf(w.w, (float)c3.h[0], ax); ay = fmaf(w.w, (float)c3.h[1], ay);
    }
    union { unsigned u; _Float16 h[2]; } p;
    p.h[0] = (_Float16)ax; p.h[1] = (_Float16)ay;
    *reinterpret_cast<unsigned*>(tmp + (size_t)(row0 + r) * 256 + h * 32 + hd2 * 2) = p.u;
}

// ---------------------------------------------------------------------------
// GEMM 3: out = tmp @ Wo + bo. A is fp16 (no cvt in staging). Row guard.
// ---------------------------------------------------------------------------
__global__ __launch_bounds__(256) void k_oproj_mm(const _Float16* __restrict__ tmp,
                                                  const _Float16* __restrict__ Wot,
                                                  const float* __restrict__ bo,
                                                  float* __restrict__ out)
{
    __shared__ _Float16 Alds[4 * 64 * 8];    //  4 KB
    __shared__ _Float16 Blds[4 * 256 * 8];   // 16 KB
    const int t = threadIdx.x;
    const int lane = t & 63, w = t >> 6;
    const int row0 = blockIdx.x * 64;

    const int srow = t & 63, skq = t >> 6;
    const _Float16* Abase = tmp + (size_t)(row0 + srow) * 256 + skq * 8;
    const uint4* Bbase = reinterpret_cast<const uint4*>(Wot + (size_t)t * 256);

    uint4 ar = *reinterpret_cast<const uint4*>(Abase);
    uint4 br[4];
#pragma unroll
    for (int i = 0; i < 4; ++i) br[i] = Bbase[i];

    f32x4 acc[4][4];
#pragma unroll
    for (int fr = 0; fr < 4; ++fr)
#pragma unroll
        for (int fc = 0; fc < 4; ++fc) acc[fr][fc] = (f32x4){0.f, 0.f, 0.f, 0.f};

    for (int kt = 0; kt < 8; ++kt) {
        *reinterpret_cast<uint4*>(&Alds[(skq * 64 + srow) * 8]) = ar;
#pragma unroll
        for (int i = 0; i < 4; ++i)
            *reinterpret_cast<uint4*>(&Blds[(i * 256 + t) * 8]) = br[i];
        if (kt < 7) {
            const int k0n = (kt + 1) * 32;
            ar = *reinterpret_cast<const uint4*>(Abase + k0n);
#pragma unroll
            for (int i = 0; i < 4; ++i) br[i] = Bbase[(kt + 1) * 4 + i];
        }
        __syncthreads();
        half8 af[4], bf[4];
#pragma unroll
        for (int fr = 0; fr < 4; ++fr)
            af[fr] = *reinterpret_cast<const half8*>(&Alds[(((lane >> 4) * 64) + fr * 16 + (lane & 15)) * 8]);
#pragma unroll
        for (int fc = 0; fc < 4; ++fc)
            bf[fc] = *reinterpret_cast<const half8*>(&Blds[(((lane >> 4) * 256) + w * 64 + fc * 16 + (lane & 15)) * 8]);
#pragma unroll
        for (int fr = 0; fr < 4; ++fr)
#pragma unroll
            for (int fc = 0; fc < 4; ++fc)
                acc[fr][fc] = __builtin_amdgcn_mfma_f32_16x16x32_f16(af[fr], bf[fc], acc[fr][fc], 0, 0, 0);
        __syncthreads();
    }

#pragma unroll
    for (int fc = 0; fc < 4; ++fc) {
        const int n = w * 64 + fc * 16 + (lane & 15);
        const float bon = bo[n];
#pragma unroll
        for (int fr = 0; fr < 4; ++fr) {
            const f32x4 c = acc[fr][fc];
#pragma unroll
            for (int j = 0; j < 4; ++j) {
                const int m = fr * 16 + (lane >> 4) * 4 + j;
                if (row0 + m < 20000)
                    out[(size_t)(row0 + m) * 256 + n] = c[j] + bon;
            }
        }
    }
}

// ---------------------------------------------------------------------------
extern "C" void kernel_launch(void* const* d_in, const int* in_sizes, int n_in,
                              void* d_out, int out_size, void* d_ws, size_t ws_size,
                              hipStream_t stream)
{
    const float* query = (const float*)d_in[0];
    const float* refp  = (const float*)d_in[1];
    const float* value = (const float*)d_in[2];
    const float* Wv = (const float*)d_in[4];
    const float* bv = (const float*)d_in[5];
    const float* Ws = (const float*)d_in[6];
    const float* bs = (const float*)d_in[7];
    const float* Wa = (const float*)d_in[8];
    const float* ba = (const float*)d_in[9];
    const float* Wo = (const float*)d_in[10];
    const float* bo = (const float*)d_in[11];
    float* out = (float*)d_out;

    char* ws = (char*)d_ws;
    // byte offsets (all 128-aligned)
    _Float16* vt_h   = (_Float16*)(ws + 0);                    // 11,141,120 h = 22,282,240 B
    _Float16* tmp_h  = (_Float16*)(ws + 22282240);             // 20032*256 h = 10,256,384 B
    _Float16* Wvt    = (_Float16*)(ws + 32538624);             // 65536 h    =    131,072 B
    _Float16* Wsat   = (_Float16*)(ws + 32669696);             // 98304 h    =    196,608 B
    _Float16* Wot    = (_Float16*)(ws + 32866304);             // 65536 h    =    131,072 B
    float*    lin    = (float*)   (ws + 32997376);             // 20032*384  = 30,769,152 B
    float*    sxg    = (float*)   (ws + 63766528);             // 10,240,000 B
    float*    syg    = (float*)   (ws + 74006528);
    float*    swg    = (float*)   (ws + 84246528);             // ends 94,486,528

    hipLaunchKernelGGL(k_prepw, dim3(896), dim3(256), 0, stream,
                       Wv, Ws, Wa, Wo, Wvt, Wsat, Wot);
    hipLaunchKernelGGL(k_vproj_mm, dim3(NB_B * NB_S / 64), dim3(256), 0, stream,
                       value, Wvt, bv, vt_h);
    hipLaunchKernelGGL(k_coords_mm, dim3(MQ_PAD / 64), dim3(256), 0, stream,
                       query, Wsat, lin);
    hipLaunchKernelGGL(k_cpost, dim3(NB_B * NB_Q / 2), dim3(256), 0, stream,
                       lin, refp, bs, ba, sxg, syg, swg);
    hipLaunchKernelGGL(k_gather, dim3(NB_B * NB_Q / 16 * NB_NH), dim3(256), 0, stream,
                       vt_h, sxg, syg, swg, tmp_h);
    hipLaunchKernelGGL(k_oproj_mm, dim3(MQ_PAD / 64), dim3(256), 0, stream,
                       tmp_h, Wot, bo, out);
}